// Round 11
// baseline (112.624 us; speedup 1.0000x reference)
//
#include <hip/hip_runtime.h>
#include <cstddef>
#include <cstdint>

// ---------------------------------------------------------------------------
// MILModel7 forward. Exact math simplification: softmax over axis=1 of
// (s_i + s_j + Wb) -> j-terms cancel -> scores = softmax(s, axis=n).
//
// R10: LDS-bandwidth diagnosis. Every wave must read the full 16 KB B-slice
// per K-step (16 B/lane/MFMA is irreducible), so the only lever is rows/wave.
// 32 rows/wave x 4 waves (128-row blocks, grid 512): B-frag read feeds 2
// row-fragments -> per-row LDS traffic halves. LDS 112 KB -> 1 block/CU
// (VGPR-rich: no spill risk). Depth-2 counted-vmcnt pipeline kept; A-loads
// via inline asm (compiler can't inject vmcnt(0)); sched_barrier(0) after
// every waitcnt/barrier pins the schedule (rule: reg-ops hoist past asm).
// ---------------------------------------------------------------------------

typedef __attribute__((ext_vector_type(8))) short short8;
typedef __attribute__((ext_vector_type(4))) float float4v;

#define MFMA16(a, b, c) __builtin_amdgcn_mfma_f32_16x16x32_bf16((a), (b), (c), 0, 0, 0)
#define VMCNT(n) asm volatile("s_waitcnt vmcnt(" #n ")" ::: "memory")
#define BARRIER() __builtin_amdgcn_s_barrier()
#define SCHED0() __builtin_amdgcn_sched_barrier(0)

__device__ __forceinline__ unsigned short f2bf(float f) {
    union { float f; unsigned u; } v; v.f = f;
    unsigned r = (v.u + 0x7fffu + ((v.u >> 16) & 1u)) >> 16;
    return (unsigned short)r;
}
__device__ __forceinline__ float bf2f(unsigned short h) {
    union { unsigned u; float f; } v; v.u = ((unsigned)h) << 16;
    return v.f;
}
__device__ __forceinline__ float bf2f_s(short h) { return bf2f((unsigned short)h); }

// truncation split: x ~= hi + lo, |err| <= 2^-16 |x|
__device__ __forceinline__ void bfsplit(float x, short& h, short& l) {
    union { float f; unsigned u; } v; v.f = x;
    h = (short)(v.u >> 16);
    union { unsigned u; float f; } hv; hv.u = v.u & 0xffff0000u;
    union { float f; unsigned u; } lv; lv.f = x - hv.f;
    l = (short)(lv.u >> 16);
}

__device__ __forceinline__ float tanh_fast(float x) {
    float e = __builtin_exp2f(x * 2.885390081777927f);
    return 1.f - 2.f / (e + 1.f);
}
__device__ __forceinline__ float sigmoid_fast(float x) {
    return 1.f / (1.f + __builtin_exp2f(-x * 1.4426950408889634f));
}

// async global->LDS, 16 B per lane (wave-uniform base + lane*16 dest).
__device__ __forceinline__ void gload_lds16(const void* g, void* l) {
#if __has_builtin(__builtin_amdgcn_global_load_lds)
    __builtin_amdgcn_global_load_lds(
        (const __attribute__((address_space(1))) unsigned int*)g,
        (__attribute__((address_space(3))) unsigned int*)l, 16, 0, 0);
#else
    *(uint4*)l = *(const uint4*)g;
#endif
}

// global -> VGPR load the compiler does NOT track (we control waits).
__device__ __forceinline__ void gload4(float4v& d, const float* p) {
    asm volatile("global_load_dwordx4 %0, %1, off"
                 : "=&v"(d) : "v"(p) : "memory");
}

// ---------------------------------------------------------------------------
// prep: split weights into bf16 (hi/lo) MFMA B-fragment layout.
// Frag layout: elem index ((nf*KS + ks)*64 + lane)*8 + j  holds
//   W[n = (lane&15)+16*nf][k = ks*32 + (lane>>4)*8 + j]
// ---------------------------------------------------------------------------
__global__ __launch_bounds__(256)
void prep(const float* __restrict__ vfc_w, const float* __restrict__ afc_w,
          const float* __restrict__ am_v_w, const float* __restrict__ am_a_w,
          const float* __restrict__ V_w,
          unsigned short* __restrict__ W1h, unsigned short* __restrict__ W1l,
          unsigned short* __restrict__ W1bh, unsigned short* __restrict__ W1bl,
          unsigned short* __restrict__ W2v, unsigned short* __restrict__ W2a,
          unsigned short* __restrict__ W3)
{
    int t = blockIdx.x * 256 + threadIdx.x;
    if (t < 65536) {                       // vfc_w (128x512), hi+lo
        int j = t & 7, lane = (t >> 3) & 63, ks = (t >> 9) & 15, nf = (t >> 13) & 7;
        int n = (lane & 15) + 16 * nf, k = ks * 32 + (lane >> 4) * 8 + j;
        float x = vfc_w[n * 512 + k];
        unsigned short h = f2bf(x);
        W1h[t] = h; W1l[t] = f2bf(x - bf2f(h));
    } else if (t < 81920) {                // afc_w (128x128), hi+lo
        int u = t - 65536;
        int j = u & 7, lane = (u >> 3) & 63, ks = (u >> 9) & 3, nf = (u >> 11) & 7;
        int n = (lane & 15) + 16 * nf, k = ks * 32 + (lane >> 4) * 8 + j;
        float x = afc_w[n * 128 + k];
        unsigned short h = f2bf(x);
        W1bh[u] = h; W1bl[u] = f2bf(x - bf2f(h));
    } else if (t < 98304) {                // am_v_w, single
        int u = t - 81920;
        int j = u & 7, lane = (u >> 3) & 63, ks = (u >> 9) & 3, nf = (u >> 11) & 7;
        int n = (lane & 15) + 16 * nf, k = ks * 32 + (lane >> 4) * 8 + j;
        W2v[u] = f2bf(am_v_w[n * 128 + k]);
    } else if (t < 114688) {               // am_a_w, single
        int u = t - 98304;
        int j = u & 7, lane = (u >> 3) & 63, ks = (u >> 9) & 3, nf = (u >> 11) & 7;
        int n = (lane & 15) + 16 * nf, k = ks * 32 + (lane >> 4) * 8 + j;
        W2a[u] = f2bf(am_a_w[n * 128 + k]);
    } else if (t < 122880) {               // V_w (64x128), single
        int u = t - 114688;
        int j = u & 7, lane = (u >> 3) & 63, ks = (u >> 9) & 3, nf = (u >> 11) & 3;
        int n = (lane & 15) + 16 * nf, k = ks * 32 + (lane >> 4) * 8 + j;
        W3[u] = f2bf(V_w[n * 128 + k]);
    }
}

// ---------------------------------------------------------------------------
// milA: fused chain. 4 waves x 32 rows = 128 rows/block, grid 512.
// LDS: bstage[3][16KB] + vo1s 32KB + axs 32KB = 112 KB -> 1 block/CU.
// Global slice schedule s=0..24: [0,16) W1 (hi,lo), [16,20) W1b, [20,24) W2
// (v,a), 24 = W3. Read slice s at global iter g=s from buf g%3; stage slice
// g+2 into buf (g+2)%3. A-batch b: [0,16) vfeat, [16,20) afeat, else none.
// ---------------------------------------------------------------------------
__global__ __launch_bounds__(256, 1)
void milA(const float* __restrict__ vfeat, const float* __restrict__ afeat,
          const float* __restrict__ vfc_b, const float* __restrict__ afc_b,
          const float* __restrict__ am_v_b, const float* __restrict__ am_a_b,
          const float* __restrict__ am_o_w, const float* __restrict__ am_o_b,
          const float* __restrict__ V_b, const float* __restrict__ W_w,
          const unsigned short* __restrict__ W1h, const unsigned short* __restrict__ W1l,
          const unsigned short* __restrict__ W1bh, const unsigned short* __restrict__ W1bl,
          const unsigned short* __restrict__ W2v, const unsigned short* __restrict__ W2a,
          const unsigned short* __restrict__ W3,
          float* __restrict__ ffeat_out, float* __restrict__ s_out)
{
    __shared__ __align__(16) unsigned short bstage[3][8192];  // 48 KB
    __shared__ __align__(16) unsigned short vo1s[16384];      // 32 KB [wid][32][128] swz
    __shared__ __align__(16) unsigned short axs[16384];       // 32 KB

    const int tid = threadIdx.x;
    const int lane = tid & 63, wid = tid >> 6;
    const int lr = lane & 15, lg = lane >> 4;
    const int row0 = blockIdx.x * 128 + wid * 32;   // flat row base (b*2048+n)

    const float* apv0 = vfeat + (size_t)(row0 + lr) * 512 + lg * 8;
    const float* apv1 = apv0 + (size_t)16 * 512;
    const float* apa0 = afeat + (size_t)(row0 + lr) * 128 + lg * 8;
    const float* apa1 = apa0 + (size_t)16 * 128;

    // stage one 16-frag (16 KB) slice; each wave stages 4 frags.
    auto stage16 = [&](const unsigned short* th, const unsigned short* tl,
                       int nks, int ks, int buf) {
#pragma unroll
        for (int i = 0; i < 4; ++i) {
            const int f = wid * 4 + i;
            const int nf = f & 7;
            const unsigned short* src = ((f >> 3) ? tl : th)
                + ((size_t)(nf * nks + ks)) * 512 + (size_t)lane * 8;
            gload_lds16(src, &bstage[buf][f * 512 + lane * 8]);
        }
    };
    auto stage_slice = [&](int s, int buf) {
        if (s < 16)      stage16(W1h,  W1l,  16, s,      buf);
        else if (s < 20) stage16(W1bh, W1bl, 4,  s - 16, buf);
        else if (s < 24) stage16(W2v,  W2a,  4,  s - 20, buf);
        else if (s == 24) {
#pragma unroll
            for (int i = 0; i < 4; ++i) {            // W3: f = nf*4+ks
                const int f = wid * 4 + i;
                gload_lds16(W3 + (size_t)f * 512 + lane * 8,
                            &bstage[buf][f * 512 + lane * 8]);
            }
        }
    };

    float4v a0[4], a1[4], a2[4];   // [rf*2+half]; 3 batches deep
    auto issueA = [&](float4v (&a)[4], int b) {      // 4 loads when b<20
        const float *p0, *p1;
        if (b < 16)      { p0 = apv0 + b * 32;        p1 = apv1 + b * 32; }
        else if (b < 20) { p0 = apa0 + (b - 16) * 32; p1 = apa1 + (b - 16) * 32; }
        else return;
        gload4(a[0], p0); gload4(a[1], p0 + 4);
        gload4(a[2], p1); gload4(a[3], p1 + 4);
    };
    auto rotA = [&]() {
#pragma unroll
        for (int q = 0; q < 4; ++q) { a0[q] = a1[q]; a1[q] = a2[q]; }
    };
    auto convA = [&](short8 (&ah)[2], short8 (&al)[2]) {
#pragma unroll
        for (int rf = 0; rf < 2; ++rf) {
            const float xs[8] = {a0[rf*2][0], a0[rf*2][1], a0[rf*2][2], a0[rf*2][3],
                                 a0[rf*2+1][0], a0[rf*2+1][1], a0[rf*2+1][2], a0[rf*2+1][3]};
#pragma unroll
            for (int j = 0; j < 8; ++j) {
                short h, l; bfsplit(xs[j], h, l);
                ah[rf][j] = h; al[rf][j] = l;
            }
        }
    };

    // ================= GEMM1: vo1 = relu(vfeat @ vfc^T + b), K=512 ============
    float4v acc1[2][8];
#pragma unroll
    for (int rf = 0; rf < 2; ++rf)
#pragma unroll
        for (int nf = 0; nf < 8; ++nf)
#pragma unroll
            for (int i = 0; i < 4; ++i) acc1[rf][nf][i] = 0.f;

    // prologue: A(0), stage(0), A(1), stage(1) -> wait oldest 8 (A0+stage0)
    issueA(a0, 0);
    stage_slice(0, 0);
    issueA(a1, 1);
    stage_slice(1, 1);
    VMCNT(8); SCHED0();
    BARRIER(); SCHED0();

    int rb = 0;                                       // read-buffer index
    for (int ks = 0; ks < 16; ++ks) {
        const int tb = (rb >= 1) ? rb - 1 : 2;        // (rb+2)%3
        issueA(a2, ks + 2);                           // 4 loads (vfeat/afeat)
        stage_slice(ks + 2, tb);                      // 4 loads
        short8 ah[2], al[2];
        convA(ah, al);
#pragma unroll
        for (int nf = 0; nf < 8; ++nf) {
            const short8 bh = *(const short8*)&bstage[rb][nf * 512 + lane * 8];
            const short8 bl = *(const short8*)&bstage[rb][(8 + nf) * 512 + lane * 8];
#pragma unroll
            for (int rf = 0; rf < 2; ++rf) {
                acc1[rf][nf] = MFMA16(ah[rf], bh, acc1[rf][nf]);
                acc1[rf][nf] = MFMA16(ah[rf], bl, acc1[rf][nf]);
                acc1[rf][nf] = MFMA16(al[rf], bh, acc1[rf][nf]);
            }
        }
        rotA();
        VMCNT(8); SCHED0();                           // A(ks+1)+stage(ks+1) done
        BARRIER(); SCHED0();
        rb = (rb < 2) ? rb + 1 : 0;
    }
    // epilogue: bias+relu (exact f32 kept in acc1), bf16 copy to swizzled LDS
#pragma unroll
    for (int rf = 0; rf < 2; ++rf)
#pragma unroll
        for (int nf = 0; nf < 8; ++nf) {
            const float bb = vfc_b[lr + 16 * nf];
#pragma unroll
            for (int r = 0; r < 4; ++r) {
                float v = fmaxf(acc1[rf][nf][r] + bb, 0.f);
                acc1[rf][nf][r] = v;
                const int row = rf * 16 + lg * 4 + r;
                const int col = lr + 16 * nf;
                vo1s[wid * 4096 + row * 128 + (col ^ ((row & 7) << 3))] = f2bf(v);
            }
        }

    // ================= GEMM1b: ax = relu(afeat @ afc^T + b), K=128 ============
    float4v acc1b[2][8];
#pragma unroll
    for (int rf = 0; rf < 2; ++rf)
#pragma unroll
        for (int nf = 0; nf < 8; ++nf)
#pragma unroll
            for (int i = 0; i < 4; ++i) acc1b[rf][nf][i] = 0.f;

    for (int ks = 0; ks < 4; ++ks) {
        const int tb = (rb >= 1) ? rb - 1 : 2;
        issueA(a2, 18 + ks);                          // apa2, apa3, none, none
        stage_slice(18 + ks, tb);                     // W1b s2,s3; W2 s0,s1
        short8 ah[2], al[2];
        convA(ah, al);
#pragma unroll
        for (int nf = 0; nf < 8; ++nf) {
            const short8 bh = *(const short8*)&bstage[rb][nf * 512 + lane * 8];
            const short8 bl = *(const short8*)&bstage[rb][(8 + nf) * 512 + lane * 8];
#pragma unroll
            for (int rf = 0; rf < 2; ++rf) {
                acc1b[rf][nf] = MFMA16(ah[rf], bh, acc1b[rf][nf]);
                acc1b[rf][nf] = MFMA16(ah[rf], bl, acc1b[rf][nf]);
                acc1b[rf][nf] = MFMA16(al[rf], bh, acc1b[rf][nf]);
            }
        }
        rotA();
        if (ks < 2) { VMCNT(8); } else { VMCNT(4); }
        SCHED0();
        BARRIER(); SCHED0();
        rb = (rb < 2) ? rb + 1 : 0;
    }
#pragma unroll
    for (int rf = 0; rf < 2; ++rf)
#pragma unroll
        for (int nf = 0; nf < 8; ++nf) {
            const float bb = afc_b[lr + 16 * nf];
#pragma unroll
            for (int r = 0; r < 4; ++r) {
                float v = fmaxf(acc1b[rf][nf][r] + bb, 0.f);
                acc1b[rf][nf][r] = v;
                const int row = rf * 16 + lg * 4 + r;
                const int col = lr + 16 * nf;
                axs[wid * 4096 + row * 128 + (col ^ ((row & 7) << 3))] = f2bf(v);
            }
        }

    // ============ GEMM2: h = vo1 @ am_v^T + ax @ am_a^T (single bf16) =========
    float4v acc2[2][8];
#pragma unroll
    for (int rf = 0; rf < 2; ++rf)
#pragma unroll
        for (int nf = 0; nf < 8; ++nf)
#pragma unroll
            for (int i = 0; i < 4; ++i) acc2[rf][nf][i] = 0.f;

    for (int ks = 0; ks < 4; ++ks) {
        const int tb = (rb >= 1) ? rb - 1 : 2;
        stage_slice(22 + ks, tb);                     // W2 s2,s3; W3; none
        short8 a2v[2], a2a[2];
#pragma unroll
        for (int rf = 0; rf < 2; ++rf) {
            const int row = rf * 16 + lr;
            const int rdoff = (ks * 32 + lg * 8) ^ ((row & 7) << 3);
            a2v[rf] = *(const short8*)&vo1s[wid * 4096 + row * 128 + rdoff];
            a2a[rf] = *(const short8*)&axs[wid * 4096 + row * 128 + rdoff];
        }
#pragma unroll
        for (int nf = 0; nf < 8; ++nf) {
            const short8 bv = *(const short8*)&bstage[rb][nf * 512 + lane * 8];
            const short8 ba = *(const short8*)&bstage[rb][(8 + nf) * 512 + lane * 8];
#pragma unroll
            for (int rf = 0; rf < 2; ++rf) {
                acc2[rf][nf] = MFMA16(a2v[rf], bv, acc2[rf][nf]);
                acc2[rf][nf] = MFMA16(a2a[rf], ba, acc2[rf][nf]);
            }
        }
        if (ks < 3) {
            VMCNT(4); SCHED0();
            BARRIER(); SCHED0();
        }
        rb = (rb < 2) ? rb + 1 : 0;
    }

    // ---- att = sigmoid(tanh(h).am_o + ob), per row ---------------------------
    float attc[2][4];
    {
        float bias2[8], wo[8];
#pragma unroll
        for (int nf = 0; nf < 8; ++nf) {
            const int c = lr + 16 * nf;
            bias2[nf] = am_v_b[c] + am_a_b[c];
            wo[nf] = am_o_w[c];
        }
        const float ob = am_o_b[0];
#pragma unroll
        for (int rf = 0; rf < 2; ++rf)
#pragma unroll
            for (int r = 0; r < 4; ++r) {
                float p = 0.f;
#pragma unroll
                for (int nf = 0; nf < 8; ++nf)
                    p += tanh_fast(acc2[rf][nf][r] + bias2[nf]) * wo[nf];
                p += __shfl_xor(p, 1);
                p += __shfl_xor(p, 2);
                p += __shfl_xor(p, 4);
                p += __shfl_xor(p, 8);
                attc[rf][r] = sigmoid_fast(p + ob);
            }
    }

    VMCNT(0); SCHED0();       // W3 stage complete (only outstanding vmem)
    BARRIER(); SCHED0();      // visible to all waves; W3 in bstage[0]

    // ---- ffeat = att*ax + vo1 (exact f32 from live accs) -> global -----------
#pragma unroll
    for (int rf = 0; rf < 2; ++rf)
#pragma unroll
        for (int nf = 0; nf < 8; ++nf)
#pragma unroll
            for (int r = 0; r < 4; ++r)
                ffeat_out[(size_t)(row0 + rf * 16 + lg * 4 + r) * 128 + lr + 16 * nf] =
                    attc[rf][r] * acc1b[rf][nf][r] + acc1[rf][nf][r];

    // att for row lr via shfl broadcast (row q owned by lanes lg=q>>2, r=q&3)
    float attv[2];
    {
        const int srcl = (lr >> 2) << 4;
#pragma unroll
        for (int rf = 0; rf < 2; ++rf) {
            const float b0 = __shfl(attc[rf][0], srcl);
            const float b1 = __shfl(attc[rf][1], srcl);
            const float b2 = __shfl(attc[rf][2], srcl);
            const float b3 = __shfl(attc[rf][3], srcl);
            attv[rf] = (lr & 2) ? ((lr & 1) ? b3 : b2) : ((lr & 1) ? b1 : b0);
        }
    }

    // ================= GEMM3: f_v = relu(ffeat @ V^T + Vb), N=64 ==============
    float4v acc3[2][4];
#pragma unroll
    for (int rf = 0; rf < 2; ++rf)
#pragma unroll
        for (int nf = 0; nf < 4; ++nf)
#pragma unroll
            for (int i = 0; i < 4; ++i) acc3[rf][nf][i] = 0.f;

#pragma unroll
    for (int ks = 0; ks < 4; ++ks) {
        short8 a3[2];
#pragma unroll
        for (int rf = 0; rf < 2; ++rf) {
            const int row = rf * 16 + lr;
            const int sidx = wid * 4096 + row * 128 + ((ks * 32 + lg * 8) ^ ((row & 7) << 3));
            const short8 x8 = *(const short8*)&axs[sidx];
            const short8 v8 = *(const short8*)&vo1s[sidx];
#pragma unroll
            for (int j = 0; j < 8; ++j) {
                float f = attv[rf] * bf2f_s(x8[j]) + bf2f_s(v8[j]);
                a3[rf][j] = (short)f2bf(f);
            }
        }
#pragma unroll
        for (int nf = 0; nf < 4; ++nf) {
            const short8 b = *(const short8*)&bstage[0][(nf * 4 + ks) * 512 + lane * 8];
#pragma unroll
            for (int rf = 0; rf < 2; ++rf) acc3[rf][nf] = MFMA16(a3[rf], b, acc3[rf][nf]);
        }
    }

    // ---- s = relu(f_v + V_b) . W_w -> ws -------------------------------------
    {
        float vb3[4], ww3[4];
#pragma unroll
        for (int nf = 0; nf < 4; ++nf) {
            const int c = lr + 16 * nf;
            vb3[nf] = V_b[c];
            ww3[nf] = W_w[c];
        }
#pragma unroll
        for (int rf = 0; rf < 2; ++rf)
#pragma unroll
            for (int r = 0; r < 4; ++r) {
                float q = 0.f;
#pragma unroll
                for (int nf = 0; nf < 4; ++nf)
                    q += fmaxf(acc3[rf][nf][r] + vb3[nf], 0.f) * ww3[nf];
                q += __shfl_xor(q, 1);
                q += __shfl_xor(q, 2);
                q += __shfl_xor(q, 4);
                q += __shfl_xor(q, 8);
                if (lr == 0) s_out[row0 + rf * 16 + lg * 4 + r] = q;
            }
    }
}

// ---------------------------------------------------------------------------
// Phase B
// ---------------------------------------------------------------------------
__device__ __forceinline__ float wred_sum(float v) {
#pragma unroll
    for (int m = 32; m >= 1; m >>= 1) v += __shfl_xor(v, m);
    return v;
}
__device__ __forceinline__ float wred_max(float v) {
#pragma unroll
    for (int m = 32; m >= 1; m >>= 1) v = fmaxf(v, __shfl_xor(v, m));
    return v;
}

__global__ __launch_bounds__(256)
void milB1(const float* __restrict__ s_in, float* __restrict__ scores_out)
{
    __shared__ float red[4];
    const int t = threadIdx.x, b = blockIdx.x, w = t >> 6;
    const float* sb = s_in + (size_t)b * 2048;

    float v[8];
#pragma unroll
    for (int q = 0; q < 8; ++q) v[q] = sb[q * 256 + t];
    float m = v[0];
#pragma unroll
    for (int q = 1; q < 8; ++q) m = fmaxf(m, v[q]);
    m = wred_max(m);
    if ((t & 63) == 0) red[w] = m;
    __syncthreads();
    const float bm = fmaxf(fmaxf(red[0], red[1]), fmaxf(red[2], red[3]));

    float e[8], sum = 0.f;
#pragma unroll
    for (int q = 0; q < 8; ++q) { e[q] = expf(v[q] - bm); sum += e[q]; }
    sum = wred_sum(sum);
    __syncthreads();
    if ((t & 63) == 0) red[w] = sum;
    __syncthreads();
    const float inv = 1.f / (red[0] + red[1] + red[2] + red[3]);
#pragma unroll
    for (int q = 0; q < 8; ++q)
        scores_out[(size_t)b * 2048 + q * 256 + t] = e[q] * inv;
}

__global__ __launch_bounds__(256)
void milB2(const float* __restrict__ scores, const float* __restrict__ ffeat,
           float* __restrict__ parts)
{
    __shared__ float sh[256];
    __shared__ float zbuf[256];
    const int t = threadIdx.x;
    const int b = blockIdx.x >> 3, part = blockIdx.x & 7;
    const int col = t & 127, half = t >> 7;

    sh[t] = scores[(size_t)b * 2048 + part * 256 + t];
    __syncthreads();

    const float* fb = ffeat + ((size_t)(b * 2048 + part * 256 + half * 128)) * 128 + col;
    const float* sp = sh + half * 128;
    float z = 0.f;
#pragma unroll 8
    for (int nn = 0; nn < 128; ++nn) z += sp[nn] * fb[(size_t)nn * 128];
    zbuf[t] = z;
    __syncthreads();
    if (t < 128) parts[((size_t)(b * 8 + part)) * 128 + t] = zbuf[t] + zbuf[t + 128];
}

__global__ __launch_bounds__(128)
void milB3(const float* __restrict__ parts, const float* __restrict__ cls_w,
           const float* __restrict__ cls_b, float* __restrict__ logits)
{
    __shared__ float zfs[128];
    const int t = threadIdx.x, b = blockIdx.x;
    float zf = 0.f;
#pragma unroll
    for (int p = 0; p < 8; ++p) zf += parts[((size_t)(b * 8 + p)) * 128 + t];
    zfs[t] = zf;
    __syncthreads();
    const int o = t >> 6, c = t & 63;
    float q = zfs[c] * cls_w[o * 128 + c] + zfs[c + 64] * cls_w[o * 128 + c + 64];
    q = wred_sum(q);
    if (c == 0) logits[b * 2 + o] = q + cls_b[o];
}

extern "C" void kernel_launch(void* const* d_in, const int* in_sizes, int n_in,
                              void* d_out, int out_size, void* d_ws, size_t ws_size,
                              hipStream_t stream)
{
    (void)in_sizes; (void)n_in; (void)out_size; (void)ws_size;
    const float* vfeat  = (const float*)d_in[0];
    const float* afeat  = (const float*)d_in[1];
    const float* vfc_w  = (const float*)d_in[2];
    const float* vfc_b  = (const float*)d_in[3];
    const float* afc_w  = (const float*)d_in[4];
    const float* afc_b  = (const float*)d_in[5];
    const float* am_v_w = (const float*)d_in[6];
    const float* am_v_b = (const float*)d_in[7];
    const float* am_a_w = (const float*)d_in[8];
    const float* am_a_b = (const float*)d_in[9];
    const float* am_o_w = (const float*)d_in[10];
    const float* am_o_b = (const float*)d_in[11];
    const float* V_w    = (const float*)d_in[12];
    const float* V_b    = (const float*)d_in[13];
    const float* W_w    = (const float*)d_in[14];
    // d_in[15] = W_b: cancels exactly in the softmax over axis=1 -> unused.
    const float* cls_w  = (const float*)d_in[16];
    const float* cls_b  = (const float*)d_in[17];

    float* scores = (float*)d_out;                 // 32*2048
    float* logits = (float*)d_out + 32 * 2048;     // 32*2

    char* ws = (char*)d_ws;
    float* ffeat_ws = (float*)ws;                              // 33,554,432 B
    float* s_ws     = (float*)(ws + 33554432);                 //    262,144 B
    float* parts_ws = (float*)(ws + 33816576);                 //    131,072 B
    unsigned short* W1h  = (unsigned short*)(ws + 33947648);   // 65536
    unsigned short* W1l  = W1h + 65536;
    unsigned short* W1bh = W1l + 65536;                        // 16384
    unsigned short* W1bl = W1bh + 16384;
    unsigned short* W2v  = W1bl + 16384;
    unsigned short* W2a  = W2v + 16384;
    unsigned short* W3   = W2a + 16384;                        // 8192; end ~34.4 MB

    prep<<<480, 256, 0, stream>>>(vfc_w, afc_w, am_v_w, am_a_w, V_w,
                                  W1h, W1l, W1bh, W1bl, W2v, W2a, W3);
    milA<<<512, 256, 0, stream>>>(vfeat, afeat, vfc_b, afc_b, am_v_b, am_a_b,
                                  am_o_w, am_o_b, V_b, W_w,
                                  W1h, W1l, W1bh, W1bl, W2v, W2a, W3,
                                  ffeat_ws, s_ws);
    milB1<<<32, 256, 0, stream>>>(s_ws, scores);
    milB2<<<256, 256, 0, stream>>>(scores, ffeat_ws, parts_ws);
    milB3<<<32, 128, 0, stream>>>(parts_ws, cls_w, cls_b, logits);
}